// Round 13
// baseline (121.261 us; speedup 1.0000x reference)
//
#include <hip/hip_runtime.h>
#include <math.h>

#define WH     256
#define NDEPTH 8
#define NBATCH 1024
#define NB     8            // batch elements per block (256 blocks, 1/CU)
#define PLANE  (WH * WH)    // 65536

typedef _Float16 h2 __attribute__((ext_vector_type(2)));

// ws layout (fp16): wsh[arr][hq][d][hs][w]
//   arr: 0=M1 1=B1 2=M2 3=B2 ; hq = h>>6 ; hs = h&63
// Per (arr,hq): 8*64*256 halfs = 256 KB. Depth stride = 2048 uint4; chunk
// (4 rows) = 128 uint4; 16 chunks/depth. Branchless ring may read <=3 chunks
// past a stream end -> lands in the following block or ws tail (ws>=8MiB, R2).
#define HQBLK  (NDEPTH * 64 * WH)   // halfs per (arr,hq) block = 131072

// Forced packed fp16 math (guard against elementwise builtins scalarizing).
static __device__ __forceinline__ h2 pk_fma(h2 a, h2 b, h2 c) {
    int r;
    const int ai = __builtin_bit_cast(int, a);
    const int bi = __builtin_bit_cast(int, b);
    const int ci = __builtin_bit_cast(int, c);
    asm("v_pk_fma_f16 %0, %1, %2, %3" : "=v"(r) : "v"(ai), "v"(bi), "v"(ci));
    return __builtin_bit_cast(h2, r);
}
static __device__ __forceinline__ h2 pk_max(h2 a, h2 b) {
    int r;
    const int ai = __builtin_bit_cast(int, a);
    const int bi = __builtin_bit_cast(int, b);
    asm("v_pk_max_f16 %0, %1, %2" : "=v"(r) : "v"(ai), "v"(bi));
    return __builtin_bit_cast(h2, r);
}

// ---------------------------------------------------------------------------
// Transpose + fp32->fp16 convert. 512 blocks x 256 threads. (~10us, unchanged)
// bid = arr(2b) | d(3b) | ht(2b) | wt(2b); 64x64 tile via fp32 LDS (pitch 65).
// ---------------------------------------------------------------------------
__global__ __launch_bounds__(256) void transpose_half_k(const float* __restrict__ M1,
                                                        const float* __restrict__ B1,
                                                        const float* __restrict__ M2,
                                                        const float* __restrict__ B2,
                                                        _Float16* __restrict__ wsh) {
    __shared__ float tile[64][65];
    const int bid = blockIdx.x;
    const int arr = bid >> 7;
    const int d   = (bid >> 4) & 7;
    const int ht  = (bid >> 2) & 3;     // h-tile == hq
    const int wt  = bid & 3;            // w-tile

    const float* src = (arr == 0) ? M1 : (arr == 1) ? B1 : (arr == 2) ? M2 : B2;
    const float* s = src + d * PLANE;
    _Float16* o = wsh + ((size_t)(arr * 4 + ht) * NDEPTH + d) * (64 * WH);

    const int t   = threadIdx.x;
    const int q16 = t >> 4;     // 0..15
    const int r16 = t & 15;     // 0..15

#pragma unroll
    for (int p = 0; p < 4; ++p) {        // read: float4 along h ([d][w][h])
        const int wrow = q16 + p * 16;
        const float4 v = *(const float4*)(s + (wt * 64 + wrow) * WH + ht * 64 + r16 * 4);
        tile[wrow][r16 * 4 + 0] = v.x;
        tile[wrow][r16 * 4 + 1] = v.y;
        tile[wrow][r16 * 4 + 2] = v.z;
        tile[wrow][r16 * 4 + 3] = v.w;
    }
    __syncthreads();
#pragma unroll
    for (int p = 0; p < 4; ++p) {        // write: 4 halfs along w
        const int hrow = q16 + p * 16;
        const int wl   = r16 * 4;
        union { _Float16 f[4]; uint2 u; } pk;
        pk.f[0] = (_Float16)tile[wl + 0][hrow];
        pk.f[1] = (_Float16)tile[wl + 1][hrow];
        pk.f[2] = (_Float16)tile[wl + 2][hrow];
        pk.f[3] = (_Float16)tile[wl + 3][hrow];
        *(uint2*)(o + hrow * WH + wt * 64 + wl) = pk.u;
    }
}

// ---------------------------------------------------------------------------
// Prop: 256 blocks x 256 threads, NB=8 (best shape: R11, 50.4us).
// *** Lore (R4-R12): 2-blocks/CU unreachable without spill; branchless ring
// *** keeps VGPR ~72; extra TLP (R12) did NOT help -> bottleneck was the
// *** LOCKSTEP L2 HOTSPOT: all 32 CUs of an XCD read identical addresses
// *** simultaneously. Fix here: per-block DE-PHASING.
//   k = bid>>3 (0..31, distinct per XCD):
//     - wave reads h-block hq = (wave + k) & 3
//     - chunks within a depth processed in rotated order (c + 2*(k>>2)) & 15
//   -> 32 CUs start 64 KB apart in the 2 MiB stream. Valid because max over
//   h is order-independent; depth order unchanged (recurrence).
// Also: packed math forced via v_pk_fma_f16/v_pk_max_f16 inline asm.
// ---------------------------------------------------------------------------
__global__ __launch_bounds__(256) void prop_h_k(const _Float16* __restrict__ wsh,
                                                const float* __restrict__ val,
                                                float* __restrict__ out) {
    const int bid  = blockIdx.x;
    const int x    = bid & 7;             // XCD hint
    const int br   = x >> 2;              // branch -> XCD half
    const int k    = bid >> 3;            // 0..31, distinct within an XCD
    const int bg   = k * 4 + (x & 3);     // 0..127
    const int t    = threadIdx.x;
    const int wave = t >> 6;
    const int lane = t & 63;

    const int hqw  = (wave + k) & 3;      // de-phased h-block assignment
    const int rot  = ((k >> 2) << 1) & 15; // chunk rotation within depth

    const int arrM = br ? 2 : 0;
    const int arrB = br ? 3 : 1;
    // uint4 units: HQBLK/8 = 16384 uint4 per (arr,hq); depth stride 2048
    const uint4* __restrict__ dAm = (const uint4*)wsh + (size_t)(arrM * 4 + hqw) * (HQBLK / 8);
    const uint4* __restrict__ dAb = (const uint4*)wsh + (size_t)(arrB * 4 + hqw) * (HQBLK / 8);

    h2 q2[NB];
#pragma unroll
    for (int nb = 0; nb < NB; ++nb) {
        const _Float16 qh = (_Float16)val[bg * NB + nb];   // block-uniform
        q2[nb].x = qh; q2[nb].y = qh;
    }

    __shared__ h2 part[8][NB][128];   // 32 KB
    __shared__ float qs[NB];

    union H8 { uint4 u; h2 h[4]; };

    // 4-slot ring, 16 uint4 = 64 VGPRs of prefetch state
    uint4 bm[4][2], bb[4][2];
#pragma unroll
    for (int s = 0; s < 3; ++s) {          // prologue: seq positions 0..2
        const int pc = (s + rot) & 15;
        const uint4* pm = dAm + pc * 128 + lane;
        const uint4* pb = dAb + pc * 128 + lane;
        bm[s][0] = pm[0]; bm[s][1] = pm[64];
        bb[s][0] = pb[0]; bb[s][1] = pb[64];
    }

    union { unsigned short us; _Float16 f; } ninf; ninf.us = 0xFC00;  // -inf
    h2 NEGINF; NEGINF.x = ninf.f; NEGINF.y = ninf.f;

    for (int d = 0; d < NDEPTH; ++d) {
        h2 acc[NB][4];
#pragma unroll
        for (int nb = 0; nb < NB; ++nb)
#pragma unroll
            for (int kk = 0; kk < 4; ++kk) acc[nb][kk] = NEGINF;

#pragma unroll
        for (int c = 0; c < 16; ++c) {
            const int slot = c & 3;
            const int ps   = (c + 3) & 3;
            // Branchless rotated prefetch of sequence position c+3.
            // (c+3<16) is compile-time: base is current or next depth;
            // ((c+3)+rot)&15 is the same formula either way (mod 16).
            const int pc2 = ((c + 3) + rot) & 15;              // uniform
            const uint4* basem = (c + 3 < 16) ? dAm : (dAm + 2048);
            const uint4* baseb = (c + 3 < 16) ? dAb : (dAb + 2048);
            const uint4* pm = basem + pc2 * 128 + lane;
            const uint4* pb = baseb + pc2 * 128 + lane;
            bm[ps][0] = pm[0]; bm[ps][1] = pm[64];
            bb[ps][0] = pb[0]; bb[ps][1] = pb[64];

            H8 m0, m1, b0, b1;
            m0.u = bm[slot][0]; m1.u = bm[slot][1];
            b0.u = bb[slot][0]; b1.u = bb[slot][1];
#pragma unroll
            for (int nb = 0; nb < NB; ++nb) {
                const h2 qq = q2[nb];
#pragma unroll
                for (int kk = 0; kk < 4; ++kk) {
                    acc[nb][kk] = pk_max(acc[nb][kk], pk_fma(qq, m0.h[kk], b0.h[kk]));
                    acc[nb][kk] = pk_max(acc[nb][kk], pk_fma(qq, m1.h[kk], b1.h[kk]));
                }
            }
        }
        dAm += 2048; dAb += 2048;          // next depth base

        // stage partials: vw = distinct 32-h subset, j32 owns w = j32*8..+7
        const int vw  = wave * 2 + (lane >> 5);
        const int j32 = lane & 31;
#pragma unroll
        for (int nb = 0; nb < NB; ++nb) {
            H8 st;
            st.h[0] = acc[nb][0]; st.h[1] = acc[nb][1];
            st.h[2] = acc[nb][2]; st.h[3] = acc[nb][3];
            *(uint4*)&part[vw][nb][j32 * 4] = st.u;
        }
        __syncthreads();

        // reduce: thread t -> nb = t>>5 (0..7), j = t&31 (w block j*8..+7)
        {
            const int nb = t >> 5;
            const int j  = t & 31;
            H8 v; v.u = *(const uint4*)&part[0][nb][j * 4];
#pragma unroll
            for (int s2 = 1; s2 < 8; ++s2) {
                H8 w2; w2.u = *(const uint4*)&part[s2][nb][j * 4];
#pragma unroll
                for (int kk = 0; kk < 4; ++kk)
                    v.h[kk] = pk_max(v.h[kk], w2.h[kk]);
            }
            h2 mn = __builtin_elementwise_min(
                        __builtin_elementwise_min(v.h[0], v.h[1]),
                        __builtin_elementwise_min(v.h[2], v.h[3]));
            float r = fminf((float)mn.x, (float)mn.y);
#pragma unroll
            for (int off = 16; off > 0; off >>= 1)
                r = fminf(r, __shfl_xor(r, off, 32));   // min within 32-lane group
            if (j == 0) qs[nb] = r;
        }
        __syncthreads();
#pragma unroll
        for (int nb = 0; nb < NB; ++nb) {
            const _Float16 qh = (_Float16)qs[nb];
            q2[nb].x = qh; q2[nb].y = qh;
        }
        // part[] rewritten only after this barrier next depth -> safe
    }

    if (t < NB) out[br * NBATCH + bg * NB + t] = qs[t];
}

// ---------------------------------------------------------------------------
extern "C" void kernel_launch(void* const* d_in, const int* in_sizes, int n_in,
                              void* d_out, int out_size, void* d_ws, size_t ws_size,
                              hipStream_t stream) {
    const float* val = (const float*)d_in[0];
    const float* M1  = (const float*)d_in[1];
    const float* B1  = (const float*)d_in[2];
    const float* M2  = (const float*)d_in[3];
    const float* B2  = (const float*)d_in[4];
    float*    out = (float*)d_out;
    _Float16* wsh = (_Float16*)d_ws;   // 4 MiB + over-read pad (ws >= 8 MiB, R2)

    transpose_half_k<<<dim3(512), dim3(256), 0, stream>>>(M1, B1, M2, B2, wsh);
    prop_h_k<<<dim3(256), dim3(256), 0, stream>>>(wsh, val, out);
}

// Round 14
// 115.867 us; speedup vs baseline: 1.0466x; 1.0466x over previous
//
#include <hip/hip_runtime.h>
#include <math.h>

#define WH     256
#define NDEPTH 8
#define NBATCH 1024
#define NB     8            // batch elements per block (256 blocks, 1/CU)
#define PLANE  (WH * WH)    // 65536

typedef _Float16 h2 __attribute__((ext_vector_type(2)));

// ws layout (fp16): wsh[arr][hq][d][hs][w]
//   arr: 0=M1 1=B1 2=M2 3=B2 ; hq = h>>6 ; hs = h&63
// Per (arr,hq): 8*64*256 halfs = 256 KB, contiguous across depth ->
// each prop wave streams ONE pointer, +2 KB per 4-row chunk, branchless.
// Pipeline over-reads <=3 chunks (6 KB) past stream end; lands in the next
// (arr,hq) block or the ws tail (ws_size >= 8 MiB, verified R2) -> harmless.
#define HQBLK  (NDEPTH * 64 * WH)   // halfs per (arr,hq) block = 131072

// ---------------------------------------------------------------------------
// Transpose + fp32->fp16 convert. 512 blocks x 256 threads. (~10us, unchanged)
// bid = arr(2b) | d(3b) | ht(2b) | wt(2b); 64x64 tile via fp32 LDS (pitch 65).
// ---------------------------------------------------------------------------
__global__ __launch_bounds__(256) void transpose_half_k(const float* __restrict__ M1,
                                                        const float* __restrict__ B1,
                                                        const float* __restrict__ M2,
                                                        const float* __restrict__ B2,
                                                        _Float16* __restrict__ wsh) {
    __shared__ float tile[64][65];
    const int bid = blockIdx.x;
    const int arr = bid >> 7;
    const int d   = (bid >> 4) & 7;
    const int ht  = (bid >> 2) & 3;     // h-tile == hq
    const int wt  = bid & 3;            // w-tile

    const float* src = (arr == 0) ? M1 : (arr == 1) ? B1 : (arr == 2) ? M2 : B2;
    const float* s = src + d * PLANE;
    _Float16* o = wsh + ((size_t)(arr * 4 + ht) * NDEPTH + d) * (64 * WH);

    const int t   = threadIdx.x;
    const int q16 = t >> 4;     // 0..15
    const int r16 = t & 15;     // 0..15

#pragma unroll
    for (int p = 0; p < 4; ++p) {        // read: float4 along h ([d][w][h])
        const int wrow = q16 + p * 16;
        const float4 v = *(const float4*)(s + (wt * 64 + wrow) * WH + ht * 64 + r16 * 4);
        tile[wrow][r16 * 4 + 0] = v.x;
        tile[wrow][r16 * 4 + 1] = v.y;
        tile[wrow][r16 * 4 + 2] = v.z;
        tile[wrow][r16 * 4 + 3] = v.w;
    }
    __syncthreads();
#pragma unroll
    for (int p = 0; p < 4; ++p) {        // write: 4 halfs along w
        const int hrow = q16 + p * 16;
        const int wl   = r16 * 4;
        union { _Float16 f[4]; uint2 u; } pk;
        pk.f[0] = (_Float16)tile[wl + 0][hrow];
        pk.f[1] = (_Float16)tile[wl + 1][hrow];
        pk.f[2] = (_Float16)tile[wl + 2][hrow];
        pk.f[3] = (_Float16)tile[wl + 3][hrow];
        *(uint2*)(o + hrow * WH + wt * 64 + wl) = pk.u;
    }
}

// ---------------------------------------------------------------------------
// Prop: 256 blocks x 256 threads, NB=8. R11 VERBATIM except ONE change:
//   hq = (wave + (bid>>3)) & 3   (was: hq = wave)
// Theory under test: same-line lockstep serialization — all 32 CUs of an
// XCD previously streamed IDENTICAL addresses in sync, so only one L2 bank
// was active at a time serving 32 copies of each line. This de-phases CUs
// into 4 groups 64 KB apart at zero inner-loop cost.
// *** Lore (R4-R13): branchless ring + running pointers keep VGPR ~72 (R11);
// *** guarded prefetch bloats VGPR + kills load hoisting (R6); min-waves
// *** launch-bounds args clamp VGPR->spill (R4/R7/R10); inline-asm pk math
// *** breaks compiler scheduling, +40us (R13); extra TLP alone: no effect
// *** (R12). Math: v_pk_fma_f16 + v_pk_max_f16 via elementwise builtins.
// ---------------------------------------------------------------------------
__global__ __launch_bounds__(256) void prop_h_k(const _Float16* __restrict__ wsh,
                                                const float* __restrict__ val,
                                                float* __restrict__ out) {
    const int bid  = blockIdx.x;
    const int x    = bid & 7;             // XCD hint
    const int br   = x >> 2;              // branch -> XCD half
    const int k    = bid >> 3;            // 0..31, distinct within an XCD
    const int bg   = k * 4 + (x & 3);     // 0..127
    const int t    = threadIdx.x;
    const int wave = t >> 6;
    const int lane = t & 63;

    const int hq   = (wave + k) & 3;      // de-phased h-block assignment

    const int arrM = br ? 2 : 0;
    const int arrB = br ? 3 : 1;
    // uint4 units: HQBLK/8 = 16384 uint4 per (arr,hq); chunk = 128 uint4
    const uint4* __restrict__ mp = (const uint4*)wsh + (size_t)(arrM * 4 + hq) * (HQBLK / 8) + lane;
    const uint4* __restrict__ bp = (const uint4*)wsh + (size_t)(arrB * 4 + hq) * (HQBLK / 8) + lane;

    h2 q2[NB];
#pragma unroll
    for (int nb = 0; nb < NB; ++nb) {
        const _Float16 qh = (_Float16)val[bg * NB + nb];   // block-uniform
        q2[nb].x = qh; q2[nb].y = qh;
    }

    __shared__ h2 part[8][NB][128];   // 32 KB: [virtual wave][nb][w/2]
    __shared__ float qs[NB];

    union H8 { uint4 u; h2 h[4]; };

    // 4-slot ring, 16 uint4 = 64 VGPRs of prefetch state
    uint4 bm[4][2], bb[4][2];
#pragma unroll
    for (int s = 0; s < 3; ++s) {          // prologue: chunks 0..2
        bm[s][0] = mp[0]; bm[s][1] = mp[64];
        bb[s][0] = bp[0]; bb[s][1] = bp[64];
        mp += 128; bp += 128;
    }

    union { unsigned short us; _Float16 f; } ninf; ninf.us = 0xFC00;  // -inf
    h2 NEGINF; NEGINF.x = ninf.f; NEGINF.y = ninf.f;

    for (int d = 0; d < NDEPTH; ++d) {
        h2 acc[NB][4];
#pragma unroll
        for (int nb = 0; nb < NB; ++nb)
#pragma unroll
            for (int kk = 0; kk < 4; ++kk) acc[nb][kk] = NEGINF;

#pragma unroll
        for (int c = 0; c < 16; ++c) {
            const int slot = c & 3;          // compile-time per unrolled iter
            const int ps   = (c + 3) & 3;
            // BRANCHLESS prefetch: may over-read <=6 KB past stream end,
            // stays inside d_ws (>=8 MiB; fp16 ws is 4 MiB). Values unused.
            bm[ps][0] = mp[0]; bm[ps][1] = mp[64];
            bb[ps][0] = bp[0]; bb[ps][1] = bp[64];
            mp += 128; bp += 128;

            H8 m0, m1, b0, b1;
            m0.u = bm[slot][0]; m1.u = bm[slot][1];
            b0.u = bb[slot][0]; b1.u = bb[slot][1];
#pragma unroll
            for (int nb = 0; nb < NB; ++nb) {
                const h2 qq = q2[nb];
#pragma unroll
                for (int kk = 0; kk < 4; ++kk) {
                    acc[nb][kk] = __builtin_elementwise_max(
                        acc[nb][kk], __builtin_elementwise_fma(qq, m0.h[kk], b0.h[kk]));
                    acc[nb][kk] = __builtin_elementwise_max(
                        acc[nb][kk], __builtin_elementwise_fma(qq, m1.h[kk], b1.h[kk]));
                }
            }
        }

        // stage partials: vw = distinct 32-h subset, j32 owns w = j32*8..+7
        const int vw  = wave * 2 + (lane >> 5);
        const int j32 = lane & 31;
#pragma unroll
        for (int nb = 0; nb < NB; ++nb) {
            H8 st;
            st.h[0] = acc[nb][0]; st.h[1] = acc[nb][1];
            st.h[2] = acc[nb][2]; st.h[3] = acc[nb][3];
            *(uint4*)&part[vw][nb][j32 * 4] = st.u;
        }
        __syncthreads();

        // reduce: thread t -> nb = t>>5 (0..7), j = t&31 (w block j*8..+7)
        {
            const int nb = t >> 5;
            const int j  = t & 31;
            H8 v; v.u = *(const uint4*)&part[0][nb][j * 4];
#pragma unroll
            for (int s2 = 1; s2 < 8; ++s2) {
                H8 w2; w2.u = *(const uint4*)&part[s2][nb][j * 4];
#pragma unroll
                for (int kk = 0; kk < 4; ++kk)
                    v.h[kk] = __builtin_elementwise_max(v.h[kk], w2.h[kk]);
            }
            h2 mn = __builtin_elementwise_min(
                        __builtin_elementwise_min(v.h[0], v.h[1]),
                        __builtin_elementwise_min(v.h[2], v.h[3]));
            float r = fminf((float)mn.x, (float)mn.y);
#pragma unroll
            for (int off = 16; off > 0; off >>= 1)
                r = fminf(r, __shfl_xor(r, off, 32));   // min within 32-lane group
            if (j == 0) qs[nb] = r;
        }
        __syncthreads();
#pragma unroll
        for (int nb = 0; nb < NB; ++nb) {
            const _Float16 qh = (_Float16)qs[nb];
            q2[nb].x = qh; q2[nb].y = qh;
        }
        // part[] rewritten only after this barrier next depth -> safe
    }

    if (t < NB) out[br * NBATCH + bg * NB + t] = qs[t];
}

// ---------------------------------------------------------------------------
extern "C" void kernel_launch(void* const* d_in, const int* in_sizes, int n_in,
                              void* d_out, int out_size, void* d_ws, size_t ws_size,
                              hipStream_t stream) {
    const float* val = (const float*)d_in[0];
    const float* M1  = (const float*)d_in[1];
    const float* B1  = (const float*)d_in[2];
    const float* M2  = (const float*)d_in[3];
    const float* B2  = (const float*)d_in[4];
    float*    out = (float*)d_out;
    _Float16* wsh = (_Float16*)d_ws;   // 4 MiB + over-read pad (ws >= 8 MiB, R2)

    transpose_half_k<<<dim3(512), dim3(256), 0, stream>>>(M1, B1, M2, B2, wsh);
    prop_h_k<<<dim3(256), dim3(256), 0, stream>>>(wsh, val, out);
}